// Round 4
// baseline (1091.515 us; speedup 1.0000x reference)
//
#include <hip/hip_runtime.h>
#include <stdint.h>

#define HH 200
#define WW 200
#define HWSZ 40000
#define NPX 80000

typedef __attribute__((ext_vector_type(8))) short bf16x8;
typedef __attribute__((ext_vector_type(4))) float f32x4;

__device__ __forceinline__ float bf2f(unsigned short u) {
    union { uint32_t i; float f; } c; c.i = ((uint32_t)u) << 16; return c.f;
}
__device__ __forceinline__ unsigned short f2bf(float f) {
    union { float f; uint32_t i; } c; c.f = f;
    uint32_t r = c.i + 0x7FFF + ((c.i >> 16) & 1);   // RNE
    return (unsigned short)(r >> 16);
}
__device__ __forceinline__ uint32_t f32u(float f) {
    union { float f; uint32_t i; } c; c.f = f; return c.i;
}
// pack 4 f32 -> 4 bf16 (RTZ truncate; used for logit scratch only)
__device__ __forceinline__ uint2 pack4_rtz(f32x4 d) {
    uint2 p;
    p.x = (f32u(d[0]) >> 16) | (f32u(d[1]) & 0xFFFF0000u);
    p.y = (f32u(d[2]) >> 16) | (f32u(d[3]) & 0xFFFF0000u);
    return p;
}
__device__ __forceinline__ void wave_fence() {
    asm volatile("s_waitcnt lgkmcnt(0)" ::: "memory");
    __builtin_amdgcn_wave_barrier();
}

// ---------------------------------------------------------------------------
// Weight conversion: fp32 -> bf16; W1/W2 transposed to [cout][cin];
// Wcat = concat(Wo, Wr) along k.
// ---------------------------------------------------------------------------
__global__ __launch_bounds__(256) void cvt_weights(
    const float* __restrict__ Wq, const float* __restrict__ Wk,
    const float* __restrict__ Wv, const float* __restrict__ Wo,
    const float* __restrict__ Wr, const float* __restrict__ W1,
    const float* __restrict__ W2,
    unsigned short* Wq_b, unsigned short* Wk_b, unsigned short* Wv_b,
    unsigned short* Wcat, unsigned short* W1t, unsigned short* W2t)
{
    const int seg = blockIdx.y;
    const int idx = blockIdx.x * 256 + threadIdx.x;
    if (seg == 0)      { if (idx < 16384) Wq_b[idx] = f2bf(Wq[idx]); }
    else if (seg == 1) { if (idx < 65536) Wk_b[idx] = f2bf(Wk[idx]); }
    else if (seg == 2) { if (idx < 65536) Wv_b[idx] = f2bf(Wv[idx]); }
    else if (seg == 3) {
        if (idx < 81920) {
            int r = idx / 320, k = idx - r * 320;
            Wcat[idx] = f2bf(k < 256 ? Wo[r * 256 + k] : Wr[r * 64 + (k - 256)]);
        }
    } else if (seg == 4) {
        if (idx < 262144) { int o = idx >> 8, i = idx & 255; W1t[idx] = f2bf(W1[i * 1024 + o]); }
    } else {
        if (idx < 262144) { int o = idx >> 10, i = idx & 1023; W2t[idx] = f2bf(W2[i * 256 + o]); }
    }
}

// ---------------------------------------------------------------------------
// NCHW fp32 -> NHWC bf16 (64px x 64c LDS tile).
// ---------------------------------------------------------------------------
__global__ __launch_bounds__(256) void to_nhwc(
    const float* __restrict__ src, unsigned short* __restrict__ dst, int C)
{
    __shared__ unsigned short T[64][72];
    const int b = blockIdx.z, c0 = blockIdx.y * 64, px0 = blockIdx.x * 64;
    const int t = threadIdx.x;
    const int pxl = t & 63, cl0 = t >> 6;
    const float* sp = src + ((size_t)(b * C + c0 + cl0)) * HWSZ + px0 + pxl;
    #pragma unroll
    for (int i = 0; i < 16; ++i)
        T[pxl][cl0 + i * 4] = f2bf(sp[(size_t)i * 4 * HWSZ]);
    __syncthreads();
    #pragma unroll
    for (int r = 0; r < 2; ++r) {
        int idx = t + r * 256;
        int p = idx >> 3, cof = (idx & 7) * 8;
        uint4 v = *(const uint4*)&T[p][cof];
        *(uint4*)(dst + ((size_t)(b * HWSZ + px0 + p)) * C + c0 + cof) = v;
    }
}

// ---------------------------------------------------------------------------
// bf16 MFMA GEMM. Out[px][cout] = sum_k In[px][k]*W[cout][k] (+bias).
// flags: 1=relu, 2=fp32 accumulate (OutF), 4=NCHW bf16 output (OutB).
// ---------------------------------------------------------------------------
__global__ __launch_bounds__(256) void gemm_bf16(
    const unsigned short* __restrict__ In, int inStride,
    const unsigned short* __restrict__ In2, int in2Stride, int K1,
    const unsigned short* __restrict__ Wb, int wStride, int Ktot,
    unsigned short* __restrict__ OutB, float* __restrict__ OutF,
    int outStride, const float* __restrict__ bias, int flags)
{
    __shared__ bf16x8 AB[1024];   // [0..511] A frags, [512..1023] B frags
    const int t = threadIdx.x;
    const int px0 = blockIdx.x * 128;
    const int n0 = blockIdx.y * 128;
    const int lane = t & 63, w = t >> 6;
    const int mh = w & 1, nh = w >> 1;

    f32x4 acc[4][4] = {};

    for (int k0 = 0; k0 < Ktot; k0 += 32) {
        #pragma unroll
        for (int r = 0; r < 2; ++r) {
            const int c = t + r * 256;
            const int l = c & 63;
            const int ko = k0 + ((l >> 4) << 3);
            {
                const int mt = c >> 6;
                const int px = px0 + mt * 16 + (l & 15);
                const unsigned short* sp = (ko < K1)
                    ? (In  + (size_t)px * inStride  + ko)
                    : (In2 + (size_t)px * in2Stride + (ko - K1));
                AB[c] = *(const bf16x8*)sp;
            }
            {
                const int nt = c >> 6;
                const int cc = n0 + nt * 16 + (l & 15);
                AB[512 + c] = *(const bf16x8*)(Wb + (size_t)cc * wStride + ko);
            }
        }
        __syncthreads();
        bf16x8 av[4], bv[4];
        #pragma unroll
        for (int i = 0; i < 4; ++i) av[i] = AB[(mh * 4 + i) * 64 + lane];
        #pragma unroll
        for (int j = 0; j < 4; ++j) bv[j] = AB[512 + (nh * 4 + j) * 64 + lane];
        #pragma unroll
        for (int i = 0; i < 4; ++i)
            #pragma unroll
            for (int j = 0; j < 4; ++j)
                acc[i][j] = __builtin_amdgcn_mfma_f32_16x16x32_bf16(
                    av[i], bv[j], acc[i][j], 0, 0, 0);
        __syncthreads();
    }

    const int q = lane >> 4, ln = lane & 15;
    const bool relu = (flags & 1) != 0, accum = (flags & 2) != 0;
    if (flags & 4) {
        // NCHW bf16 output (V path): per frag, 4 consecutive px -> uint2 store
        #pragma unroll
        for (int i = 0; i < 4; ++i) {
            #pragma unroll
            for (int j = 0; j < 4; ++j) {
                const int coutv = n0 + nh * 64 + j * 16 + ln;
                const int pxb = px0 + mh * 64 + i * 16 + q * 4;
                const int bb = pxb >= HWSZ;
                const int hw = pxb - bb * HWSZ;
                uint2 pk;
                pk.x = ((uint32_t)f2bf(acc[i][j][0])) | ((uint32_t)f2bf(acc[i][j][1]) << 16);
                pk.y = ((uint32_t)f2bf(acc[i][j][2])) | ((uint32_t)f2bf(acc[i][j][3]) << 16);
                *(uint2*)(OutB + ((size_t)(bb * 256 + coutv)) * HWSZ + hw) = pk;
            }
        }
        return;
    }
    #pragma unroll
    for (int i = 0; i < 4; ++i) {
        #pragma unroll
        for (int j = 0; j < 4; ++j) {
            const int coutv = n0 + nh * 64 + j * 16 + ln;
            const float bval = bias ? bias[coutv] : 0.0f;
            #pragma unroll
            for (int r = 0; r < 4; ++r) {
                const int px = px0 + mh * 64 + i * 16 + q * 4 + r;
                float v = acc[i][j][r] + bval;
                if (relu) v = fmaxf(v, 0.0f);
                if (OutB) {
                    OutB[(size_t)px * outStride + coutv] = f2bf(v);
                } else {
                    float* op = OutF + (size_t)px * outStride + coutv;
                    if (accum) v += *op;
                    *op = v;
                }
            }
        }
    }
}

// ---------------------------------------------------------------------------
// MFMA 7x7 local-window attention.
// Block = (b, head, 16x16 px tile), 4 waves, each wave = 4 query rows,
// fully wave-independent (no __syncthreads). Per query row:
//   QK: A-frag = Q[q][c] (global NHWC), B-frags = K[key][c] (global NHWC),
//       14 MFMAs (7 dy x 2 key halves) -> logits to per-wave LDS scratch.
//   softmax: 1 query per lane (16 q x 4 dy-groups), shuffle-reduce, p -> LDS.
//   PV: A-frag = P[q][k] built in-register from LDS band reads;
//       B-frags = V^T[c][col] read directly from global NCHW bf16 V.
// Halo col base = w0-4 (even => 4B-aligned V vector loads); k=col index,
// actual halo u = k-1, band for query q: k in [q+1, q+7]; P=0 elsewhere.
// A may alias Q (block reads only its own region before writing).
// ---------------------------------------------------------------------------
__global__ __launch_bounds__(256) void attn_mfma(
    const unsigned short* Q, const unsigned short* __restrict__ K,
    const unsigned short* __restrict__ Vn,   // NCHW bf16
    unsigned short* A)
{
    __shared__ unsigned short sc[4][7][24][16];   // [wave][dy][halo-col u][q]

    const int b = blockIdx.z, head = blockIdx.y;
    const int tiy = blockIdx.x / 13, tix = blockIdx.x % 13;
    const int h0 = tiy * 16, w0 = tix * 16;
    const int t = threadIdx.x;
    const int w = t >> 6, lane = t & 63;
    const int ln = lane & 15, kq = lane >> 4;
    const int co = head * 32;
    const bool interior = (tix >= 1) && (tix <= 10);

    // per-lane clamped columns
    const int gwq = min(w0 + ln, WW - 1);                       // Q col
    const int gw0 = min(max(w0 - 3 + ln, 0), WW - 1);           // K half0
    const int gw1 = min(max(w0 + 13 + ln, 0), WW - 1);          // K half1

    const f32x4 zf = {};

    #pragma unroll 1
    for (int rr = 0; rr < 4; ++rr) {
        const int qr = w * 4 + rr;
        const int h = h0 + qr;
        if (h >= HH) continue;   // wave-uniform

        // ---- QK phase ----
        const bf16x8 af = *(const bf16x8*)(
            Q + ((size_t)(b * HWSZ + h * WW + gwq)) * 256 + co + kq * 8);
        #pragma unroll
        for (int dy = 0; dy < 7; ++dy) {
            const int ghr = min(max(h0 + qr + dy - 3, 0), HH - 1);
            const unsigned short* kb =
                K + ((size_t)(b * HWSZ + ghr * WW)) * 256 + co + kq * 8;
            bf16x8 b0 = *(const bf16x8*)(kb + (size_t)gw0 * 256);
            bf16x8 b1 = *(const bf16x8*)(kb + (size_t)gw1 * 256);
            f32x4 d0 = __builtin_amdgcn_mfma_f32_16x16x32_bf16(af, b0, zf, 0, 0, 0);
            f32x4 d1 = __builtin_amdgcn_mfma_f32_16x16x32_bf16(af, b1, zf, 0, 0, 0);
            // D: col(key)=ln, rows(q)=kq*4+r  ->  sc[dy][col][q]
            *(uint2*)&sc[w][dy][ln][kq * 4] = pack4_rtz(d0);
            if (ln < 6)
                *(uint2*)&sc[w][dy][16 + ln][kq * 4] = pack4_rtz(d1);
        }
        wave_fence();

        // ---- softmax (query = ln; dy-group = kq: dy in {kq, kq+4}) ----
        {
            float e[14];
            float mx = -1e30f;
            #pragma unroll
            for (int d2 = 0; d2 < 2; ++d2) {
                const int dy = kq + d2 * 4;
                #pragma unroll
                for (int dx = 0; dx < 7; ++dx) {
                    float v = (dy < 7)
                        ? bf2f(sc[w][dy][ln + dx][ln]) * 0.17677669529663687f
                        : -1e30f;
                    e[d2 * 7 + dx] = v;
                    mx = fmaxf(mx, v);
                }
            }
            mx = fmaxf(mx, __shfl_xor(mx, 16));
            mx = fmaxf(mx, __shfl_xor(mx, 32));
            float s = 0.0f;
            #pragma unroll
            for (int n = 0; n < 14; ++n) { e[n] = __expf(e[n] - mx); s += e[n]; }
            s += __shfl_xor(s, 16);
            s += __shfl_xor(s, 32);
            const float inv = 1.0f / s;
            #pragma unroll
            for (int d2 = 0; d2 < 2; ++d2) {
                const int dy = kq + d2 * 4;
                if (dy < 7) {
                    #pragma unroll
                    for (int dx = 0; dx < 7; ++dx) {
                        uint32_t u = f32u(e[d2 * 7 + dx] * inv);
                        sc[w][dy][ln + dx][ln] = (unsigned short)(u >> 16);
                    }
                }
            }
        }
        wave_fence();

        // ---- PV phase ----
        f32x4 o0 = {}, o1 = {};
        #pragma unroll
        for (int dy = 0; dy < 7; ++dy) {
            const int ghr = min(max(h0 + qr + dy - 3, 0), HH - 1);
            // A-frag: P[q=ln][k=kq*8+j], band k in [ln+1, ln+7]
            union { unsigned short u[8]; bf16x8 v; } pf;
            #pragma unroll
            for (int j = 0; j < 8; ++j) {
                const int k = kq * 8 + j;
                const int d = k - 1 - ln;
                const int kc = (d >= 0 && d <= 6) ? (k - 1) : 0;
                unsigned short pv = sc[w][dy][kc][ln];
                pf.u[j] = (d >= 0 && d <= 6) ? pv : (unsigned short)0;
            }
            // B-frags: V^T[c][col] from global NCHW
            union { unsigned short u[8]; bf16x8 v; } v0, v1;
            if (interior) {
                const unsigned short* vb = Vn + (size_t)(b * 256 + co) * HWSZ
                                              + ghr * WW + (w0 - 4) + kq * 8;
                v0.v = *(const bf16x8*)(vb + (size_t)ln * HWSZ);
                v1.v = *(const bf16x8*)(vb + (size_t)(16 + ln) * HWSZ);
            } else {
                const unsigned short* vb = Vn + (size_t)(b * 256 + co) * HWSZ
                                              + ghr * WW;
                #pragma unroll
                for (int j = 0; j < 8; ++j) {
                    const int gw = min(max(w0 - 4 + kq * 8 + j, 0), WW - 1);
                    v0.u[j] = vb[(size_t)ln * HWSZ + gw];
                    v1.u[j] = vb[(size_t)(16 + ln) * HWSZ + gw];
                }
            }
            o0 = __builtin_amdgcn_mfma_f32_16x16x32_bf16(pf.v, v0.v, o0, 0, 0, 0);
            o1 = __builtin_amdgcn_mfma_f32_16x16x32_bf16(pf.v, v1.v, o1, 0, 0, 0);
        }

        // ---- store: D col(c)=ln, rows(q)=kq*4+r ----
        #pragma unroll
        for (int r = 0; r < 4; ++r) {
            const int qq = kq * 4 + r;
            const int wqv = w0 + qq;
            if (wqv < WW) {
                unsigned short* ap =
                    A + ((size_t)(b * HWSZ + h * WW + wqv)) * 256 + co;
                ap[ln] = f2bf(o0[r]);
                ap[16 + ln] = f2bf(o1[r]);
            }
        }
        wave_fence();   // protect sc before next qrow's QK writes
    }
}

// ---------------------------------------------------------------------------
// LN1: wave-per-pixel (NHWC fp32 in, bf16 out).
// ---------------------------------------------------------------------------
__global__ __launch_bounds__(256) void ln1_k(
    const float* __restrict__ X, const float* __restrict__ g,
    const float* __restrict__ bt, unsigned short* __restrict__ XLb)
{
    const int wv = threadIdx.x >> 6, lane = threadIdx.x & 63;
    const size_t px = (size_t)blockIdx.x * 4 + wv;
    const float4 v = *(const float4*)(X + px * 256 + lane * 4);
    float s = v.x + v.y + v.z + v.w;
    float ss = v.x * v.x + v.y * v.y + v.z * v.z + v.w * v.w;
    #pragma unroll
    for (int o = 32; o; o >>= 1) { s += __shfl_xor(s, o); ss += __shfl_xor(ss, o); }
    const float mu = s * (1.0f / 256.0f);
    const float var = ss * (1.0f / 256.0f) - mu * mu;
    const float rs = rsqrtf(var + 1e-5f);
    const float4 gv = *(const float4*)(g + lane * 4);
    const float4 bv = *(const float4*)(bt + lane * 4);
    ushort4 o4;
    o4.x = f2bf((v.x - mu) * rs * gv.x + bv.x);
    o4.y = f2bf((v.y - mu) * rs * gv.y + bv.y);
    o4.z = f2bf((v.z - mu) * rs * gv.z + bv.z);
    o4.w = f2bf((v.w - mu) * rs * gv.w + bv.w);
    *(ushort4*)(XLb + px * 256 + lane * 4) = o4;
}

// ---------------------------------------------------------------------------
// LN2: (bf16 XL + fp32 Y2) -> LN -> NCHW fp32 out, via LDS transpose.
// ---------------------------------------------------------------------------
__global__ __launch_bounds__(256) void ln2_k(
    const unsigned short* __restrict__ XLb, const float* __restrict__ Y2,
    const float* __restrict__ g, const float* __restrict__ bt,
    float* __restrict__ Out)
{
    __shared__ float T[256 * 33];
    const int px0 = blockIdx.x * 32;
    const int bb = px0 / HWSZ, hw0 = px0 - bb * HWSZ;
    const int t = threadIdx.x, wv = t >> 6, lane = t & 63;
    const float4 gv = *(const float4*)(g + lane * 4);
    const float4 bv = *(const float4*)(bt + lane * 4);
    #pragma unroll
    for (int it = 0; it < 8; ++it) {
        const int pxl = wv * 8 + it;
        const size_t px = (size_t)px0 + pxl;
        const ushort4 xb = *(const ushort4*)(XLb + px * 256 + lane * 4);
        const float4 y = *(const float4*)(Y2 + px * 256 + lane * 4);
        float4 v;
        v.x = bf2f(xb.x) + y.x; v.y = bf2f(xb.y) + y.y;
        v.z = bf2f(xb.z) + y.z; v.w = bf2f(xb.w) + y.w;
        float s = v.x + v.y + v.z + v.w;
        float ss = v.x * v.x + v.y * v.y + v.z * v.z + v.w * v.w;
        #pragma unroll
        for (int o = 32; o; o >>= 1) { s += __shfl_xor(s, o); ss += __shfl_xor(ss, o); }
        const float mu = s * (1.0f / 256.0f);
        const float rs = rsqrtf(ss * (1.0f / 256.0f) - mu * mu + 1e-5f);
        T[(lane * 4 + 0) * 33 + pxl] = (v.x - mu) * rs * gv.x + bv.x;
        T[(lane * 4 + 1) * 33 + pxl] = (v.y - mu) * rs * gv.y + bv.y;
        T[(lane * 4 + 2) * 33 + pxl] = (v.z - mu) * rs * gv.z + bv.z;
        T[(lane * 4 + 3) * 33 + pxl] = (v.w - mu) * rs * gv.w + bv.w;
    }
    __syncthreads();
    #pragma unroll
    for (int pass = 0; pass < 32; ++pass) {
        const int idx = t + pass * 256;
        const int c = idx >> 5, pxl = idx & 31;
        Out[((size_t)(bb * 256 + c)) * HWSZ + hw0 + pxl] = T[c * 33 + pxl];
    }
}

// ---------------------------------------------------------------------------
// Workspace (bytes), total 216.6 MB:
//   0         : Fl NHWC bf16 (10.24 MB) } dead after out-proj
//   10240000  : Fc NHWC bf16 (40.96)    }  -> Y1c [80000][512] bf16 (81.92)
//   51200000  : Qb/Ab NHWC bf16 (40.96) }     spans 0..81.92
//   92160000  : Kb NHWC bf16 (40.96)  } dead after attn
//   133120000 : Vb NCHW bf16 (40.96)  }  -> Y2 fp32 (81.92) spans 92.16..174.08
//   174080000 : XLb NHWC bf16 (40.96)
//   215040000 : bf16 weights (~1.5 MB)
//   d_out     : XW fp32 scratch -> final NCHW output
// ---------------------------------------------------------------------------
extern "C" void kernel_launch(void* const* d_in, const int* in_sizes, int n_in,
                              void* d_out, int out_size, void* d_ws, size_t ws_size,
                              hipStream_t stream)
{
    const float* F_lidar = (const float*)d_in[0];
    const float* F_cam   = (const float*)d_in[1];
    const float* Wq  = (const float*)d_in[2];
    const float* Wk  = (const float*)d_in[3];
    const float* Wv  = (const float*)d_in[4];
    const float* Wo  = (const float*)d_in[5];
    const float* Wr  = (const float*)d_in[6];
    const float* g1  = (const float*)d_in[7];
    const float* b1  = (const float*)d_in[8];
    const float* g2  = (const float*)d_in[9];
    const float* b2  = (const float*)d_in[10];
    const float* W1  = (const float*)d_in[11];
    const float* bf1 = (const float*)d_in[12];
    const float* W2  = (const float*)d_in[13];
    const float* bf2 = (const float*)d_in[14];

    char* wsb = (char*)d_ws;
    unsigned short* Fl  = (unsigned short*)(wsb);
    unsigned short* Fc  = (unsigned short*)(wsb + 10240000);
    unsigned short* Qb  = (unsigned short*)(wsb + 51200000);
    unsigned short* Kb  = (unsigned short*)(wsb + 92160000);
    unsigned short* Vb  = (unsigned short*)(wsb + 133120000);
    unsigned short* Y1c = (unsigned short*)(wsb);             // [80000][512]
    float*          Y2  = (float*)(wsb + 92160000);           // [80000][256]
    unsigned short* XLb = (unsigned short*)(wsb + 174080000);
    unsigned short* Wq_b = (unsigned short*)(wsb + 215040000);
    unsigned short* Wk_b = Wq_b + 16384;
    unsigned short* Wv_b = Wk_b + 65536;
    unsigned short* Wcat = Wv_b + 65536;
    unsigned short* W1t  = Wcat + 81920;
    unsigned short* W2t  = W1t + 262144;
    float* XW  = (float*)d_out;
    float* out = (float*)d_out;

    const dim3 blk(256);

    cvt_weights<<<dim3(1024, 6), blk, 0, stream>>>(Wq, Wk, Wv, Wo, Wr, W1, W2,
        Wq_b, Wk_b, Wv_b, Wcat, W1t, W2t);
    to_nhwc<<<dim3(625, 1, 2), blk, 0, stream>>>(F_lidar, Fl, 64);
    to_nhwc<<<dim3(625, 4, 2), blk, 0, stream>>>(F_cam, Fc, 256);

    // projections: Q,K -> NHWC bf16; V -> NCHW bf16 (flag 4)
    gemm_bf16<<<dim3(625, 2), blk, 0, stream>>>(Fl, 64, Fl, 64, 64,
        Wq_b, 64, 64, Qb, nullptr, 256, nullptr, 0);
    gemm_bf16<<<dim3(625, 2), blk, 0, stream>>>(Fc, 256, Fc, 256, 256,
        Wk_b, 256, 256, Kb, nullptr, 256, nullptr, 0);
    gemm_bf16<<<dim3(625, 2), blk, 0, stream>>>(Fc, 256, Fc, 256, 256,
        Wv_b, 256, 256, Vb, nullptr, 256, nullptr, 4);

    // MFMA local-window attention (A overwrites Q in-place)
    attn_mfma<<<dim3(169, 8, 2), blk, 0, stream>>>(Qb, Kb, Vb, Qb);

    // fused out-proj + lidar residual (K=320 concat) -> fp32 XW in d_out
    gemm_bf16<<<dim3(625, 2), blk, 0, stream>>>(Qb, 256, Fl, 64, 256,
        Wcat, 320, 320, nullptr, XW, 256, nullptr, 0);

    // LN1 -> bf16 XLb
    ln1_k<<<dim3(20000), blk, 0, stream>>>(XW, g1, b1, XLb);

    // FFN, hidden chunked 2 x 512
    for (int c = 0; c < 2; ++c) {
        gemm_bf16<<<dim3(625, 4), blk, 0, stream>>>(XLb, 256, XLb, 256, 256,
            W1t + (size_t)c * 512 * 256, 256, 256, Y1c, nullptr, 512,
            bf1 + c * 512, 1);
        gemm_bf16<<<dim3(625, 2), blk, 0, stream>>>(Y1c, 512, Y1c, 512, 512,
            W2t + c * 512, 1024, 512, nullptr, Y2, 256,
            (c == 0) ? bf2 : nullptr, (c == 0) ? 0 : 2);
    }

    // LN2 (XLb + Y2) -> final NCHW output
    ln2_k<<<dim3(2500), blk, 0, stream>>>(XLb, Y2, g2, b2, out);
}